// Round 3
// baseline (91.760 us; speedup 1.0000x reference)
//
#include <hip/hip_runtime.h>
#include <hip/hip_bf16.h>
#include <math.h>

typedef __bf16 bf16x8 __attribute__((ext_vector_type(8)));
typedef float f32x4 __attribute__((ext_vector_type(4)));

#define N_TOT 8192
#define HALF_N 4096
#define D 128
#define INV_T 14.285714285714286f
#define CSC 20.609929155556627f   /* (1/0.07) * log2(e) */
#define LN2F 0.69314718055994531f
#define NEG_BIG -1.0e38f
#define CS 16                     /* column chunks (8192/512) */
#define COLS_B 512                /* cols per block */
#define NBUF 8                    /* 512 / 64 */

__device__ __forceinline__ unsigned short f2bf(float f) {
    union { float f; unsigned int u; } a; a.f = f;
    unsigned int u = a.u;
    return (unsigned short)((u + 0x7fffu + ((u >> 16) & 1u)) >> 16);
}

// ---------- kernel 1: fused fp32->bf16 cvt + positive dots ----------
__global__ __launch_bounds__(256)
void prep_kernel(const float* __restrict__ in, unsigned short* __restrict__ fb,
                 float* __restrict__ posb) {
    const int bid = blockIdx.x;
    if (bid < 1024) {
        int i = bid * 256 + threadIdx.x;
        float4 v = reinterpret_cast<const float4*>(in)[i];
        ushort4 o;
        o.x = f2bf(v.x); o.y = f2bf(v.y); o.z = f2bf(v.z); o.w = f2bf(v.w);
        reinterpret_cast<ushort4*>(fb)[i] = o;
    } else {
        const int row  = (bid - 1024) * 4 + (threadIdx.x >> 6);
        const int lane = threadIdx.x & 63;
        const float2 a = reinterpret_cast<const float2*>(in + (size_t)row * D)[lane];
        const float2 b = reinterpret_cast<const float2*>(in + (size_t)(row ^ HALF_N) * D)[lane];
        float dot = a.x * b.x + a.y * b.y;
#pragma unroll
        for (int off = 32; off > 0; off >>= 1) dot += __shfl_xor(dot, off, 64);
        if (lane == 0) posb[row] = dot * INV_T;
    }
}

// ---------- kernel 2: fused sim + partial logsumexp ----------
// grid (128, 16). Block: 64 rows x 512 cols, 4 waves; wave w owns rows
// [bx*64 + w*16, +16). B staged in LDS (64-col double-buffered, XOR-swizzled),
// shared by all 4 waves. Per-wave (m,s) partials, no cross-wave merge.
__global__ __launch_bounds__(256, 5)
void simclr_kernel(const unsigned short* __restrict__ Fb,
                   float* __restrict__ pm, float* __restrict__ ps) {
    __shared__ unsigned short lds[2][64 * D];   // 2 x 16 KB
    const int tid  = threadIdx.x;
    const int lane = tid & 63;
    const int wid  = tid >> 6;
    const int lr   = lane & 15;
    const int lg   = lane >> 4;
    const int row0w = blockIdx.x * 64 + wid * 16;
    const int cbase = blockIdx.y * COLS_B;

    // A fragments: rows row0w+lr, k-slices kk*32 + lg*8
    bf16x8 a[4];
#pragma unroll
    for (int kk = 0; kk < 4; ++kk)
        a[kk] = *reinterpret_cast<const bf16x8*>(
            Fb + (size_t)(row0w + lr) * D + kk * 32 + lg * 8);

    float m[4], s[4];
#pragma unroll
    for (int r = 0; r < 4; ++r) { m[r] = 0.f; s[r] = 0.f; }

    // staging: thread handles 16B chunks c = tid + 256*i; col=c>>4, j=c&15
    const int scol = tid >> 4;
    const int sj   = tid & 15;

    float4 st[4];
#pragma unroll
    for (int i = 0; i < 4; ++i) {
        const int col = scol + 16 * i;
        st[i] = *reinterpret_cast<const float4*>(Fb + (size_t)(cbase + col) * D + sj * 8);
    }
#pragma unroll
    for (int i = 0; i < 4; ++i) {
        const int col = scol + 16 * i;
        *reinterpret_cast<float4*>(&lds[0][col * D + ((sj ^ (col & 7)) * 8)]) = st[i];
    }
    __syncthreads();

#pragma unroll 1
    for (int t = 0; t < NBUF; ++t) {
        const int bsel = t & 1;
        if (t + 1 < NBUF) {   // issue next-buffer loads early (T14)
#pragma unroll
            for (int i = 0; i < 4; ++i) {
                const int col = scol + 16 * i;
                st[i] = *reinterpret_cast<const float4*>(
                    Fb + (size_t)(cbase + (t + 1) * 64 + col) * D + sj * 8);
            }
        }
        const unsigned short* L = lds[bsel];
#pragma unroll
        for (int p = 0; p < 2; ++p) {
            bf16x8 b0[4], b1[4];
#pragma unroll
            for (int kk = 0; kk < 4; ++kk) {
                const int j0 = (kk * 4 + lg) ^ (lr & 7);
                b0[kk] = *reinterpret_cast<const bf16x8*>(L + ((2 * p) * 16 + lr) * D + j0 * 8);
                b1[kk] = *reinterpret_cast<const bf16x8*>(L + ((2 * p + 1) * 16 + lr) * D + j0 * 8);
            }
            f32x4 accA = {0.f, 0.f, 0.f, 0.f}, accB = {0.f, 0.f, 0.f, 0.f};
#pragma unroll
            for (int kk = 0; kk < 4; ++kk) {
                accA = __builtin_amdgcn_mfma_f32_16x16x32_bf16(a[kk], b0[kk], accA, 0, 0, 0);
                accB = __builtin_amdgcn_mfma_f32_16x16x32_bf16(a[kk], b1[kk], accB, 0, 0, 0);
            }
            const int c0g = cbase + t * 64 + p * 32;
            const bool dA = (c0g == row0w);        // wave-uniform
            const bool dB = (c0g + 16 == row0w);
#pragma unroll
            for (int r = 0; r < 4; ++r) {
                float v1 = accA[r] * CSC;
                float v2 = accB[r] * CSC;
                if (dA) { if (lr == lg * 4 + r) v1 = NEG_BIG; }
                if (dB) { if (lr == lg * 4 + r) v2 = NEG_BIG; }
                const float mo = m[r];
                const float mn = fmaxf(fmaxf(mo, v1), v2);
                const float e0 = __builtin_amdgcn_exp2f(mo - mn);
                const float e1 = __builtin_amdgcn_exp2f(v1 - mn);
                const float e2 = __builtin_amdgcn_exp2f(v2 - mn);
                s[r] = fmaf(s[r], e0, e1 + e2);
                m[r] = mn;
            }
        }
        if (t + 1 < NBUF) {   // write next buffer (loads have landed under compute)
#pragma unroll
            for (int i = 0; i < 4; ++i) {
                const int col = scol + 16 * i;
                *reinterpret_cast<float4*>(&lds[bsel ^ 1][col * D + ((sj ^ (col & 7)) * 8)]) = st[i];
            }
        }
        __syncthreads();
    }

    // 16-lane butterfly (lanes differing in low 4 bits share rows, disjoint cols)
#pragma unroll
    for (int r = 0; r < 4; ++r) {
        float M = m[r];
#pragma unroll
        for (int off = 1; off < 16; off <<= 1) M = fmaxf(M, __shfl_xor(M, off, 64));
        float sc = s[r] * __builtin_amdgcn_exp2f(m[r] - M);
#pragma unroll
        for (int off = 1; off < 16; off <<= 1) sc += __shfl_xor(sc, off, 64);
        if (lr == 0) {
            const int row = row0w + lg * 4 + r;
            pm[blockIdx.y * N_TOT + row] = M;
            ps[blockIdx.y * N_TOT + row] = sc;
        }
    }
}

// ---------- kernel 3a: merge chunk partials -> per-row loss ----------
__global__ __launch_bounds__(256)
void rowloss_kernel(const float* __restrict__ pm, const float* __restrict__ ps,
                    const float* __restrict__ posb, float* __restrict__ rowloss) {
    const int row = blockIdx.x * 256 + threadIdx.x;
    float M = pm[row], S = ps[row];
#pragma unroll
    for (int c = 1; c < CS; ++c) {
        const float Mo = pm[c * N_TOT + row], So = ps[c * N_TOT + row];
        const float mn = fmaxf(M, Mo);
        S = fmaf(S, __builtin_amdgcn_exp2f(M - mn), So * __builtin_amdgcn_exp2f(Mo - mn));
        M = mn;
    }
    rowloss[row] = LN2F * (M + __builtin_amdgcn_logf(S)) - posb[row];
}

// ---------- kernel 3b: mean ----------
__global__ __launch_bounds__(256)
void mean_kernel(const float* __restrict__ rowloss, float* __restrict__ out) {
    float acc = 0.f;
    for (int i = threadIdx.x; i < N_TOT; i += 256) acc += rowloss[i];
#pragma unroll
    for (int off = 32; off > 0; off >>= 1) acc += __shfl_xor(acc, off, 64);
    __shared__ float ls[4];
    if ((threadIdx.x & 63) == 0) ls[threadIdx.x >> 6] = acc;
    __syncthreads();
    if (threadIdx.x == 0)
        out[0] = (ls[0] + ls[1] + ls[2] + ls[3]) * (1.0f / (float)N_TOT);
}

extern "C" void kernel_launch(void* const* d_in, const int* in_sizes, int n_in,
                              void* d_out, int out_size, void* d_ws, size_t ws_size,
                              hipStream_t stream) {
    const float* feat = (const float*)d_in[0];
    char* ws = (char*)d_ws;
    unsigned short* fb = (unsigned short*)ws;                                  // 2 MB
    float* pm      = (float*)(ws + (size_t)N_TOT * D * 2);                     // 512 KB
    float* ps      = (float*)(ws + (size_t)N_TOT * D * 2 + (size_t)CS * N_TOT * 4);       // 512 KB
    float* posb    = (float*)(ws + (size_t)N_TOT * D * 2 + 2 * (size_t)CS * N_TOT * 4);   // 32 KB
    float* rowloss = (float*)(ws + (size_t)N_TOT * D * 2 + 2 * (size_t)CS * N_TOT * 4 + N_TOT * 4);
    float* out = (float*)d_out;

    prep_kernel<<<3072, 256, 0, stream>>>(feat, fb, posb);
    simclr_kernel<<<dim3(128, CS), 256, 0, stream>>>(fb, pm, ps);
    rowloss_kernel<<<N_TOT / 256, 256, 0, stream>>>(pm, ps, posb, rowloss);
    mean_kernel<<<1, 256, 0, stream>>>(rowloss, out);
}

// Round 4
// 64.066 us; speedup vs baseline: 1.4323x; 1.4323x over previous
//
#include <hip/hip_runtime.h>
#include <math.h>

typedef __bf16 bf16x8 __attribute__((ext_vector_type(8)));
typedef float f32x4 __attribute__((ext_vector_type(4)));

#define N_TOT 8192
#define HALF_N 4096
#define D 128
#define INV_T 14.285714285714286f
#define CSC 20.609929155556627f    /* (1/0.07) * log2(e) */
#define NCSC -20.609929155556627f
#define LN2F 0.69314718055994531f
#define NEG_BIG -3.0e38f
#define M_INIT -1.0e30f
#define CS 8                        /* column chunks of 1024; wave covers 256 */

__device__ __forceinline__ unsigned short f2bf(float f) {
    union { float f; unsigned int u; } a; a.f = f;
    unsigned int u = a.u;
    return (unsigned short)((u + 0x7fffu + ((u >> 16) & 1u)) >> 16);
}

// ---------- kernel 1: fp32 -> bf16 (RNE), 8 elems/thread ----------
__global__ __launch_bounds__(256)
void cvt_kernel(const float* __restrict__ in, unsigned short* __restrict__ fb) {
    const int i = blockIdx.x * 256 + threadIdx.x;
    const float4 v0 = reinterpret_cast<const float4*>(in)[2 * i];
    const float4 v1 = reinterpret_cast<const float4*>(in)[2 * i + 1];
    ushort4 o0, o1;
    o0.x = f2bf(v0.x); o0.y = f2bf(v0.y); o0.z = f2bf(v0.z); o0.w = f2bf(v0.w);
    o1.x = f2bf(v1.x); o1.y = f2bf(v1.y); o1.z = f2bf(v1.z); o1.w = f2bf(v1.w);
    reinterpret_cast<ushort4*>(fb)[2 * i] = o0;
    reinterpret_cast<ushort4*>(fb)[2 * i + 1] = o1;
}

// ---------- kernel 2: fused sim + online logsumexp (swapped operands) ----------
// grid (128, 8), 256 thr = 4 waves. Block: 64 rows; wave w streams cols
// [cy*1024 + w*256, +256) in 16-col tiles, direct from L2 (no LDS staging).
// mfma(colfrag, rowfrag): lane holds 4 consecutive COLS of row (row0+rt*16+lr).
__global__ __launch_bounds__(256)
void simclr_kernel(const unsigned short* __restrict__ Fb,
                   float* __restrict__ pm, float* __restrict__ ps,
                   float* __restrict__ rowpos) {
    const int tid  = threadIdx.x;
    const int lane = tid & 63;
    const int wid  = tid >> 6;
    const int lr   = lane & 15;
    const int lg   = lane >> 4;
    const int row0 = blockIdx.x * 64;
    const int c0w  = blockIdx.y * 1024 + wid * 256;

    auto ld = [&](int col, int kk) -> bf16x8 {
        return *reinterpret_cast<const bf16x8*>(
            Fb + (size_t)col * D + kk * 32 + lg * 8);
    };

    // held B-operand: 64 rows (4 row-tiles)
    bf16x8 br[4][4];
#pragma unroll
    for (int rt = 0; rt < 4; ++rt)
#pragma unroll
        for (int kk = 0; kk < 4; ++kk)
            br[rt][kk] = ld(row0 + rt * 16 + lr, kk);

    float m[4], s[4];
#pragma unroll
    for (int rt = 0; rt < 4; ++rt) { m[rt] = M_INIT; s[rt] = 0.f; }

    auto body = [&](const bf16x8 (&cf)[4], int t) {
        f32x4 acc[4];
#pragma unroll
        for (int rt = 0; rt < 4; ++rt) acc[rt] = f32x4{0.f, 0.f, 0.f, 0.f};
#pragma unroll
        for (int kk = 0; kk < 4; ++kk)
#pragma unroll
            for (int rt = 0; rt < 4; ++rt)
                acc[rt] = __builtin_amdgcn_mfma_f32_16x16x32_bf16(cf[kk], br[rt][kk], acc[rt], 0, 0, 0);
        const int c0 = c0w + t * 16;
#pragma unroll
        for (int rt = 0; rt < 4; ++rt) {
            const int rowbase = row0 + rt * 16;   // lane's row = rowbase + lr
            f32x4 v = acc[rt];
            if (c0 == (rowbase ^ HALF_N)) {       // wave-uniform: positive tile
#pragma unroll
                for (int r = 0; r < 4; ++r)
                    if (lr == lg * 4 + r) rowpos[rowbase + lr] = v[r];
            }
            if (c0 == rowbase) {                  // wave-uniform: diagonal tile
#pragma unroll
                for (int r = 0; r < 4; ++r)
                    if (lr == lg * 4 + r) v[r] = NEG_BIG;
            }
            const float rmax = fmaxf(fmaxf(v[0], v[1]), fmaxf(v[2], v[3]));
            const float mo = m[rt];
            const float mn = fmaxf(mo, rmax);     // raw-dot units
            const float cm = mn * NCSC;
            const float e0 = __builtin_amdgcn_exp2f(fmaf(mo,  CSC, cm));
            const float e1 = __builtin_amdgcn_exp2f(fmaf(v[0], CSC, cm));
            const float e2 = __builtin_amdgcn_exp2f(fmaf(v[1], CSC, cm));
            const float e3 = __builtin_amdgcn_exp2f(fmaf(v[2], CSC, cm));
            const float e4 = __builtin_amdgcn_exp2f(fmaf(v[3], CSC, cm));
            s[rt] = fmaf(s[rt], e0, (e1 + e2) + (e3 + e4));
            m[rt] = mn;
        }
    };

    bf16x8 ca[4], cb[4];
#pragma unroll
    for (int kk = 0; kk < 4; ++kk) ca[kk] = ld(c0w + lr, kk);

#pragma unroll 1
    for (int tp = 0; tp < 8; ++tp) {
        const int t0 = tp * 2;
#pragma unroll
        for (int kk = 0; kk < 4; ++kk) cb[kk] = ld(c0w + (t0 + 1) * 16 + lr, kk);
        body(ca, t0);
        if (tp < 7) {
#pragma unroll
            for (int kk = 0; kk < 4; ++kk) ca[kk] = ld(c0w + (t0 + 2) * 16 + lr, kk);
        }
        body(cb, t0 + 1);
    }

    // row-reduce: lanes sharing a row differ only in lg -> 2 shuffles
    __shared__ float red_m[4][64], red_s[4][64];
#pragma unroll
    for (int rt = 0; rt < 4; ++rt) {
        float M = m[rt];
        M = fmaxf(M, __shfl_xor(M, 16, 64));
        M = fmaxf(M, __shfl_xor(M, 32, 64));
        float sc = s[rt] * __builtin_amdgcn_exp2f(fmaf(m[rt], CSC, M * NCSC));
        sc += __shfl_xor(sc, 16, 64);
        sc += __shfl_xor(sc, 32, 64);
        if (lg == 0) { red_m[wid][rt * 16 + lr] = M; red_s[wid][rt * 16 + lr] = sc; }
    }
    __syncthreads();
    if (tid < 64) {   // merge the block's 4 waves (disjoint col ranges)
        float M = red_m[0][tid], S = red_s[0][tid];
#pragma unroll
        for (int w = 1; w < 4; ++w) {
            const float Mo = red_m[w][tid], So = red_s[w][tid];
            const float mn = fmaxf(M, Mo);
            S = fmaf(S,  __builtin_amdgcn_exp2f(fmaf(M,  CSC, mn * NCSC)),
                     So * __builtin_amdgcn_exp2f(fmaf(Mo, CSC, mn * NCSC)));
            M = mn;
        }
        pm[blockIdx.y * N_TOT + row0 + tid] = M;   // raw-units max
        ps[blockIdx.y * N_TOT + row0 + tid] = S;   // sum of exp2(CSC*(v-M))
    }
}

// ---------- kernel 3: merge chunks, per-row loss, mean ----------
__global__ __launch_bounds__(1024)
void finalize_kernel(const float* __restrict__ pm, const float* __restrict__ ps,
                     const float* __restrict__ rowpos, float* __restrict__ out) {
    const int tid = threadIdx.x;
    float acc = 0.f;
#pragma unroll 1
    for (int row = tid; row < N_TOT; row += 1024) {
        float M = pm[row], S = ps[row];
#pragma unroll
        for (int c = 1; c < CS; ++c) {
            const float Mo = pm[c * N_TOT + row], So = ps[c * N_TOT + row];
            const float mn = fmaxf(M, Mo);
            S = fmaf(S,  __builtin_amdgcn_exp2f(fmaf(M,  CSC, mn * NCSC)),
                     So * __builtin_amdgcn_exp2f(fmaf(Mo, CSC, mn * NCSC)));
            M = mn;
        }
        // lse_nat = ln2 * (M*CSC + log2(S)); pos_nat = rawdot * (1/T)
        acc += LN2F * fmaf(M, CSC, __builtin_amdgcn_logf(S)) - rowpos[row] * INV_T;
    }
#pragma unroll
    for (int off = 32; off > 0; off >>= 1) acc += __shfl_xor(acc, off, 64);
    __shared__ float ls[16];
    if ((tid & 63) == 0) ls[tid >> 6] = acc;
    __syncthreads();
    if (tid == 0) {
        float t = 0.f;
#pragma unroll
        for (int w = 0; w < 16; ++w) t += ls[w];
        out[0] = t * (1.0f / (float)N_TOT);
    }
}

extern "C" void kernel_launch(void* const* d_in, const int* in_sizes, int n_in,
                              void* d_out, int out_size, void* d_ws, size_t ws_size,
                              hipStream_t stream) {
    const float* feat = (const float*)d_in[0];
    char* ws = (char*)d_ws;
    unsigned short* fb = (unsigned short*)ws;                                   // 2 MB
    float* pm     = (float*)(ws + (size_t)N_TOT * D * 2);                       // 256 KB
    float* ps     = (float*)(ws + (size_t)N_TOT * D * 2 + (size_t)CS * N_TOT * 4);        // 256 KB
    float* rowpos = (float*)(ws + (size_t)N_TOT * D * 2 + 2 * (size_t)CS * N_TOT * 4);    // 32 KB
    float* out = (float*)d_out;

    cvt_kernel<<<512, 256, 0, stream>>>(feat, fb);
    simclr_kernel<<<dim3(128, CS), 256, 0, stream>>>(fb, pm, ps, rowpos);
    finalize_kernel<<<1, 1024, 0, stream>>>(pm, ps, rowpos, out);
}